// Round 19
// baseline (150.094 us; speedup 1.0000x reference)
//
#include <hip/hip_runtime.h>
#include <stdint.h>

typedef __attribute__((ext_vector_type(8))) short short8;
typedef __attribute__((ext_vector_type(4))) short short4v;
typedef __attribute__((ext_vector_type(4))) float f32x4;
typedef __attribute__((ext_vector_type(2))) unsigned int uint2v;

#define S_LEN 4096
#define NBATCH 2
#define DMODEL 768
#define NH 12
#define HD 64
#define MROWS (S_LEN * NBATCH)   // 8192

__device__ __forceinline__ unsigned short f2bf(float f) {
    unsigned int u = __builtin_bit_cast(unsigned int, f);
    u += 0x7fffu + ((u >> 16) & 1u);       // round-to-nearest-even
    return (unsigned short)(u >> 16);
}

// async global->LDS, 16B per lane; LDS dst = wave-uniform base + lane*16,
// global src is PER-LANE.
#define GLDS16(gp, lp) __builtin_amdgcn_global_load_lds( \
    (const __attribute__((address_space(1))) void*)(gp), \
    (__attribute__((address_space(3))) void*)(lp), 16, 0, 0)

#define MFMA_BF16 __builtin_amdgcn_mfma_f32_16x16x32_bf16

// ---------------- kernel 1: val fp32 -> X bf16 (8192 x 768) ----------------
__global__ __launch_bounds__(256) void cvt_val_kernel(const float* __restrict__ in,
                                                      short* __restrict__ out) {
    size_t i = (size_t)blockIdx.x * 256 + threadIdx.x;
    const f32x4 v = *(const f32x4*)(in + i * 4);
    short4v o;
    o.x = (short)f2bf(v.x); o.y = (short)f2bf(v.y);
    o.z = (short)f2bf(v.z); o.w = (short)f2bf(v.w);
    *(short4v*)(out + i * 4) = o;
}

// --- kernel 2: W fp32 (K x N) -> WT bf16 (z-major, [nf][k]) ---
__global__ __launch_bounds__(256) void cvt_w_kernel(const float* __restrict__ Wq,
                                                    const float* __restrict__ Wk,
                                                    const float* __restrict__ Wv,
                                                    short* __restrict__ WT) {
    const int z = blockIdx.z;
    const float* W = (z == 0) ? Wq : ((z == 1) ? Wk : Wv);
    const int n  = blockIdx.x * 256 + threadIdx.x;
    const int k0 = blockIdx.y * 8;
    short8 o;
#pragma unroll
    for (int i = 0; i < 8; ++i)
        o[i] = (short)f2bf(W[(size_t)(k0 + i) * DMODEL + n]);
    *(short8*)(WT + (size_t)z * DMODEL * DMODEL + (size_t)n * DMODEL + k0) = o;
}

// ------- kernel 3: fused QKV GEMM, 128x192 tile, 4 waves, wave tile 64x96 -------
// acc 4x6, 2-buffer 2-barrier counted-vmcnt (5 loads per STAGE -> vmcnt(5)),
// 3 blocks/CU. z==2 written transposed ([bh][e][s]).
#define NT 24   // 768/32 K-steps
__global__ __launch_bounds__(256, 3) void gemm_qkv_kernel(
    const short* __restrict__ X, const short* __restrict__ WT,
    const float* __restrict__ bq, const float* __restrict__ bk, const float* __restrict__ bv,
    short* __restrict__ Q, short* __restrict__ K, short* __restrict__ Vt)
{
    __shared__ __align__(16) short SMEM[26112];  // 51KB: stage A[2][4096]|B[2][6144]; C reuse
    short* As = SMEM;            // 2 * 4096 shorts
    short* Bs = SMEM + 8192;     // 2 * 6144 shorts

    const int phys = blockIdx.x;                 // 768 = 8 XCD * (8 m * 12 n), n-fastest
    const int xcd = phys & 7, ii = phys >> 3;
    const int m0  = (xcd * 8 + ii / 12) * 128;
    const int nf  = (ii % 12) * 192;
    const int z   = nf / DMODEL;                 // 4 n-tiles per z (exact boundaries)
    const int n0w = nf - z * DMODEL;

    const int tid = threadIdx.x, lane = tid & 63, wid = tid >> 6;
    const int wm = wid >> 1, wn = wid & 1;       // 2M x 2N waves, wave tile 64x96
    const int fr = lane & 15, kg = lane >> 4;
    const int wr = wm * 64, wc = wn * 96;

    const float* bias = (z == 0) ? bq : ((z == 1) ? bk : bv);
    short*       OUT  = (z == 0) ? Q  : ((z == 1) ? K  : Vt);

    f32x4 acc[4][6];
#pragma unroll
    for (int i = 0; i < 4; ++i)
#pragma unroll
        for (int j = 0; j < 6; ++j) acc[i][j] = (f32x4){0.f, 0.f, 0.f, 0.f};

    const int gslot = (lane & 3) ^ ((lane >> 3) & 3);
    const short* srcA = X  + (size_t)(m0 + wid * 32 + (lane >> 2)) * DMODEL + gslot * 8;
    const short* srcB = WT + (size_t)(nf + wid * 48 + (lane >> 2)) * DMODEL + gslot * 8;

#define STAGE(buf, kt) do { \
        GLDS16(srcA + (kt),               As + (buf) * 4096 + wid * 1024);        \
        GLDS16(srcA + (kt) + 16 * DMODEL, As + (buf) * 4096 + wid * 1024 + 512);  \
        GLDS16(srcB + (kt),               Bs + (buf) * 6144 + wid * 1536);        \
        GLDS16(srcB + (kt) + 16 * DMODEL, Bs + (buf) * 6144 + wid * 1536 + 512);  \
        GLDS16(srcB + (kt) + 32 * DMODEL, Bs + (buf) * 6144 + wid * 1536 + 1024); \
    } while (0)

    STAGE(0, 0);
    STAGE(1, 32);
    asm volatile("s_waitcnt vmcnt(5)" ::: "memory");   // tile0 (5 loads) done; tile1 in flight
    __builtin_amdgcn_sched_barrier(0);
    __builtin_amdgcn_s_barrier();

    const int rslot = (fr >> 1) & 3;             // read-side swizzle (same involution)
    for (int t = 0; t < NT; ++t) {
        const short* Ab = As + (t & 1) * 4096;
        const short* Bb = Bs + (t & 1) * 6144;
        short8 af[4], bfv[6];
#pragma unroll
        for (int mi = 0; mi < 4; ++mi)
            af[mi] = *(const short8*)(Ab + (wr + mi * 16 + fr) * 32 + (kg ^ rslot) * 8);
#pragma unroll
        for (int nj = 0; nj < 6; ++nj)
            bfv[nj] = *(const short8*)(Bb + (wc + nj * 16 + fr) * 32 + (kg ^ rslot) * 8);
        asm volatile("s_waitcnt lgkmcnt(0)" ::: "memory");   // my reads done
        __builtin_amdgcn_sched_barrier(0);
        __builtin_amdgcn_s_barrier();            // B1: ALL waves' reads of buf[t&1] done
        __builtin_amdgcn_sched_barrier(0);
        if (t + 2 < NT) STAGE(t & 1, (t + 2) * 32);          // WAR-safe overwrite
        __builtin_amdgcn_sched_barrier(0);

        __builtin_amdgcn_s_setprio(1);           // MFMA hides glds issue + latency
#pragma unroll
        for (int mi = 0; mi < 4; ++mi)
#pragma unroll
            for (int nj = 0; nj < 6; ++nj)
                acc[mi][nj] = MFMA_BF16(af[mi], bfv[nj], acc[mi][nj], 0, 0, 0);
        __builtin_amdgcn_s_setprio(0);

        // counted gate: wait tile t+1 (5 oldest); leave tile t+2's 5 in flight
        if (t + 2 < NT) { asm volatile("s_waitcnt vmcnt(5)" ::: "memory"); }
        else            { asm volatile("s_waitcnt vmcnt(0)" ::: "memory"); }
        __builtin_amdgcn_sched_barrier(0);
        __builtin_amdgcn_s_barrier();            // B2: tile t+1 visible to all waves
    }
#undef STAGE

    const float scale = (z == 0) ? 0.18033688f : 1.0f;  // q: 1/sqrt(64) * log2(e)
    float bval[6];
#pragma unroll
    for (int nj = 0; nj < 6; ++nj) bval[nj] = bias[n0w + wc + nj * 16 + fr];

    if (z < 2) {                            // Q/K: [bh][s][e], coalesced short8
        short* Cs = SMEM;                   // [128][200] bf16 (25600 <= 26112)
#pragma unroll
        for (int mi = 0; mi < 4; ++mi)
#pragma unroll
            for (int nj = 0; nj < 6; ++nj)
#pragma unroll
                for (int r = 0; r < 4; ++r)
                    Cs[(wr + mi * 16 + 4 * kg + r) * 200 + (wc + nj * 16 + fr)] =
                        (short)f2bf((acc[mi][nj][r] + bval[nj]) * scale);
        __syncthreads();
#pragma unroll
        for (int it = 0; it < 12; ++it) {   // 3072 chunks of 8 elems
            const int flat = it * 256 + tid;
            const int row = flat / 24, c8 = (flat % 24) * 8;
            const int gm = m0 + row, gn = n0w + c8;
            const int s = gm >> 1, bb = gm & 1, hh = gn >> 6, e0 = gn & 63;
            *(short8*)(&OUT[((size_t)(bb * NH + hh) * S_LEN + s) * HD + e0]) =
                *(const short8*)(&Cs[row * 200 + c8]);
        }
    } else {                                // V: write transposed [bh][e][s]
        short* Ct = SMEM;                   // [192 cols][136]: b-deinterleaved rows
#pragma unroll
        for (int mi = 0; mi < 4; ++mi)
#pragma unroll
            for (int nj = 0; nj < 6; ++nj)
#pragma unroll
                for (int r = 0; r < 4; ++r) {
                    const int row = wr + mi * 16 + 4 * kg + r;
                    const int col = wc + nj * 16 + fr;
                    Ct[col * 136 + (row & 1) * 68 + (row >> 1)] =
                        (short)f2bf(acc[mi][nj][r] + bval[nj]);
                }
        __syncthreads();
#pragma unroll
        for (int it = 0; it < 12; ++it) {   // 8B-aligned LDS reads, coalesced stores
            const int flat = it * 256 + tid;
            const int col = flat >> 4;              // 0..191
            const int b   = (flat >> 3) & 1;
            const int sc  = flat & 7;               // 8-s chunk
            const short* base = &Ct[col * 136 + b * 68 + sc * 8];
            short8 v;
            *(short4v*)&v      = *(const short4v*)(base);
            *((short4v*)&v + 1) = *(const short4v*)(base + 4);
            const int e = col & 63, hl = col >> 6;
            const int bh = b * NH + (n0w >> 6) + hl;
            *(short8*)(&OUT[(size_t)bh * HD * S_LEN + (size_t)e * S_LEN
                            + (m0 >> 1) + sc * 8]) = v;
        }
    }
}

// ------- kernel 4: flash banded attention: block = (bh, 128 q), 3 kv-tiles dbuf -------
// R18 + wave-uniform inactive-subtile skip: softmax/pack loops guarded by the
// same u in [0,16] activity test as QK^T (-29% exp2/pack work, same results).
#define PCST  40

__global__ __launch_bounds__(512, 4) void attn_kernel(
    const short* __restrict__ Q, const short* __restrict__ K,
    const short* __restrict__ Vt, float* __restrict__ out)
{
    __shared__ __align__(16) short KS[2 * 8192];       // 32 KB (2 slots)
    __shared__ __align__(16) short VS[2 * 8192];       // 32 KB
    __shared__ __align__(16) short Pc[8][16 * PCST];   // 10 KB

    const int tid = threadIdx.x, lane = tid & 63, w = tid >> 6;
    const int id = blockIdx.x;                   // 768 blocks; XCD owns 3 heads
    const int logical = (id & 7) * 96 + (id >> 3);
    const int bx = logical & 31;                 // q-tile index (128 q)
    const int bh = logical >> 5;                 // batch*head
    const int bb = bh / NH, hh = bh % NH;
    const int fr = lane & 15, g = lane >> 4;
    const int q0 = bx * 128;
    const int kstart = q0 - 256;
    const int e0m = fr - 4 * g;

    const short* Qb = Q  + (size_t)bh * S_LEN * HD;
    const short* Kb = K  + (size_t)bh * S_LEN * HD;
    const short* Vb = Vt + (size_t)bh * HD * S_LEN;

#define STAGESEG(slot, kb) do {                                                \
        const int _kc = (kb) < 0 ? 0 : (kb);                                   \
        _Pragma("unroll")                                                      \
        for (int _j = 0; _j < 2; ++_j) {  /* K [128row][8ch], swz ch^row&7 */  \
            const int _p = _j * 512 + tid;                                     \
            const int _row = _p >> 3, _ch = _p & 7;                            \
            GLDS16(Kb + (size_t)(_kc * 128 + _row) * HD + (_ch ^ (_row & 7)) * 8, \
                   KS + (slot) * 8192 + _p * 8);                               \
        }                                                                      \
        _Pragma("unroll")                                                      \
        for (int _j = 0; _j < 2; ++_j) {  /* V [64e][16ch], swz ch^e&7 */      \
            const int _p = _j * 512 + tid;                                     \
            const int _e = _p >> 4, _ch = _p & 15;                             \
            GLDS16(Vb + (size_t)_e * S_LEN + _kc * 128 + ((_ch ^ (_e & 7)) * 8), \
                   VS + (slot) * 8192 + _p * 8);                               \
        }                                                                      \
    } while (0)

    // ---- Q fragments first (oldest in vmcnt queue, drained by prologue wait) ----
    const int qrow = q0 + w * 16 + fr;
    const short8 qa0 = *(const short8*)(Qb + (size_t)qrow * HD + g * 8);
    const short8 qa1 = *(const short8*)(Qb + (size_t)qrow * HD + 32 + g * 8);

    const int kb0 = bx - 2;                      // first kv-tile index
    STAGESEG(0, kb0);
    STAGESEG(1, kb0 + 1);
    asm volatile("s_waitcnt vmcnt(4)" ::: "memory");   // Q + tile0 done; tile1 in flight
    __builtin_amdgcn_sched_barrier(0);
    __builtin_amdgcn_s_barrier();

    const bool interior = (kstart >= 0);
    float m = -1e30f, l = 0.f;
    f32x4 o[4];
#pragma unroll
    for (int et = 0; et < 4; ++et) o[et] = (f32x4){0.f, 0.f, 0.f, 0.f};

#pragma unroll
    for (int c = 0; c < 3; ++c) {
        const int slot = c & 1;
        const short* Kt = KS + slot * 8192;
        const short* Vtile = VS + slot * 8192;

        // ---- QK^T on this tile's 8 subtiles (active: u in [0,16]) ----
        float sc[8][4];
        unsigned int pk[8][2];
        float tm[8];
#pragma unroll
        for (int s = 0; s < 8; ++s) {
            const int u = 8 * c + s - w;             // wave-uniform
            if (u >= 0 && u <= 16) {
                const int row = s * 16 + fr;
                const short* kb8 = Kt + row * 64;
                const short8 a0 = *(const short8*)(kb8 + (g ^ (fr & 7)) * 8);
                const short8 a1 = *(const short8*)(kb8 + ((4 + g) ^ (fr & 7)) * 8);
                f32x4 d = {0.f, 0.f, 0.f, 0.f};
                d = MFMA_BF16(a0, qa0, d, 0, 0, 0);
                d = MFMA_BF16(a1, qa1, d, 0, 0, 0);
                if (interior) {
                    if (u == 0) {
#pragma unroll
                        for (int r = 0; r < 4; ++r) sc[s][r] = (e0m <= r) ? d[r] : -3e38f;
                    } else if (u == 16) {
#pragma unroll
                        for (int r = 0; r < 4; ++r) sc[s][r] = (e0m >= r) ? d[r] : -3e38f;
                    } else {
#pragma unroll
                        for (int r = 0; r < 4; ++r) sc[s][r] = d[r];
                    }
                } else {
                    const int gk0 = kstart + (8 * c + s) * 16 + 4 * g;
#pragma unroll
                    for (int r = 0; r < 4; ++r) {
                        const int dd = 256 + fr - 16 * u - 4 * g - r;
                        const bool ok = (dd >= 0) & (dd <= 256) & (gk0 + r >= 0);
                        sc[s][r] = ok ? d[r] : -3e38f;
                    }
                }
                tm[s] = fmaxf(fmaxf(sc[s][0], sc[s][1]), fmaxf(sc[s][2], sc[s][3]));
            } else {
                tm[s] = -3e38f;
            }
        }

        // ---- tile max tree + defer-max rescale (T13) ----
#pragma unroll
        for (int st = 1; st < 8; st <<= 1)
#pragma unroll
            for (int i = 0; i + st < 8; i += 2 * st) tm[i] = fmaxf(tm[i], tm[i + st]);
        float tmax = fmaxf(tm[0], __shfl_xor(tm[0], 16));
        tmax = fmaxf(tmax, __shfl_xor(tmax, 32));

        if (!__all(tmax - m <= 11.5f)) {         // rescale only when max grows
            const float nm = fmaxf(m, tmax);
            const float esc = exp2f(m - nm);     // scale for query fr
            float es4[4];
#pragma unroll
            for (int r = 0; r < 4; ++r) es4[r] = __shfl(esc, 4 * g + r);
#pragma unroll
            for (int et = 0; et < 4; ++et)
#pragma unroll
                for (int r = 0; r < 4; ++r) o[et][r] *= es4[r];
            l *= esc;
            m = nm;
        }

        // ---- exp2 + sum + pack, ACTIVE subtiles only (wave-uniform skip) ----
        float ts[8];
#pragma unroll
        for (int s = 0; s < 8; ++s) {
            const int u = 8 * c + s - w;
            if (u >= 0 && u <= 16) {
#pragma unroll
                for (int r = 0; r < 4; ++r) sc[s][r] = exp2f(sc[s][r] - m);
                ts[s] = (sc[s][0] + sc[s][1]) + (sc[s][2] + sc[s][3]);
                pk[s][0] = (unsigned)f2bf(sc[s][0]) | ((unsigned)f2bf(sc[s][1]) << 16);
                pk[s][1] = (unsigned)f2bf(sc[s][2]) | ((unsigned)f2bf(sc[s][3]) << 16);
            } else {
                ts[s] = 0.f;
                pk[s][0] = 0u;
                pk[s][1] = 0u;
            }
        }
#pragma unroll
        for (int st = 1; st < 8; st <<= 1)
#pragma unroll
            for (int i = 0; i + st < 8; i += 2 * st) ts[i] += ts[i + st];
        float tsum = ts[0] + __shfl_xor(ts[0], 16);
        tsum += __shfl_xor(tsum, 32);
        l += tsum;

        // ---- PV on active 32-key chunks ----
        short* pb = &Pc[w][0];
#pragma unroll
        for (int i = 0; i < 4; ++i) {
            const int slo = 8 * c + 2 * i, shi = slo + 1;   // global subtiles
            if (shi >= w && slo <= w + 16) {                // wave-uniform
                *(uint2v*)(pb + fr * PCST + 4 * g)      = (uint2v){pk[2 * i][0], pk[2 * i][1]};
                *(uint2v*)(pb + fr * PCST + 16 + 4 * g) = (uint2v){pk[2 * i + 1][0], pk[2 * i + 1][1]};
                const short8 pa = *(const short8*)(pb + fr * PCST + 8 * g);
                const int lc = 4 * i + g;                   // logical V chunk in tile
                const short* vb8 = Vtile + fr * 128 + ((lc ^ (fr & 7)) * 8);
                __builtin_amdgcn_s_setprio(1);
#pragma unroll
                for (int et = 0; et < 4; ++et) {
                    const short8 vb = *(const short8*)(vb8 + et * 2048);
                    o[et] = MFMA_BF16(pa, vb, o[et], 0, 0, 0);
                }
                __builtin_amdgcn_s_setprio(0);
            }
        }

        // ---- stage tile c+2 into this slot; ensure tile c+1 landed ----
        if (c == 0) {
            __builtin_amdgcn_s_barrier();            // all waves done with slot 0
            STAGESEG(0, kb0 + 2);
            asm volatile("s_waitcnt vmcnt(4)" ::: "memory");   // tile1 landed
            __builtin_amdgcn_sched_barrier(0);
            __builtin_amdgcn_s_barrier();
        } else if (c == 1) {
            __builtin_amdgcn_s_barrier();
            asm volatile("s_waitcnt vmcnt(0)" ::: "memory");   // tile2 landed
            __builtin_amdgcn_sched_barrier(0);
            __builtin_amdgcn_s_barrier();
        }
    }
#undef STAGESEG

    const float inv = 1.0f / l;                    // valid for query = fr
    float inv4[4];
#pragma unroll
    for (int r = 0; r < 4; ++r) inv4[r] = __shfl(inv, 4 * g + r);

#pragma unroll
    for (int et = 0; et < 4; ++et)
#pragma unroll
        for (int r = 0; r < 4; ++r) {
            const int qi = q0 + w * 16 + 4 * g + r;
            const int dd = hh * HD + et * 16 + fr;
            out[((size_t)qi * NBATCH + bb) * DMODEL + dd] = o[et][r] * inv4[r];
        }
}

extern "C" void kernel_launch(void* const* d_in, const int* in_sizes, int n_in,
                              void* d_out, int out_size, void* d_ws, size_t ws_size,
                              hipStream_t stream) {
    (void)in_sizes; (void)n_in; (void)out_size; (void)ws_size;
    const float* val = (const float*)d_in[0];
    const float* Wq  = (const float*)d_in[1];
    const float* bq  = (const float*)d_in[2];
    const float* Wk  = (const float*)d_in[3];
    const float* bk  = (const float*)d_in[4];
    const float* Wv  = (const float*)d_in[5];
    const float* bv  = (const float*)d_in[6];
    float* out = (float*)d_out;

    char* ws = (char*)d_ws;
    const size_t SZ_X  = (size_t)MROWS * DMODEL * 2;
    const size_t SZ_W  = (size_t)DMODEL * DMODEL * 2;
    short* X  = (short*)(ws);
    short* WT = (short*)(ws + SZ_X);
    short* Qb = (short*)(ws + SZ_X + 3 * SZ_W);
    short* Kb = (short*)(ws + SZ_X + 3 * SZ_W + SZ_X);
    short* Vt = (short*)(ws + SZ_X + 3 * SZ_W + 2 * SZ_X);

    cvt_val_kernel<<<dim3((MROWS * DMODEL) / 4 / 256), dim3(256), 0, stream>>>(val, X);
    cvt_w_kernel<<<dim3(3, 96, 3), dim3(256), 0, stream>>>(Wq, Wk, Wv, WT);
    gemm_qkv_kernel<<<dim3(768), dim3(256), 0, stream>>>(
        X, WT, bq, bk, bv, Qb, Kb, Vt);
    attn_kernel<<<dim3(768), dim3(512), 0, stream>>>(Qb, Kb, Vt, out);
}

// Round 20
// 76.856 us; speedup vs baseline: 1.9529x; 1.9529x over previous
//
#include <hip/hip_runtime.h>
#include <stdint.h>

typedef __attribute__((ext_vector_type(8))) short short8;
typedef __attribute__((ext_vector_type(4))) short short4v;
typedef __attribute__((ext_vector_type(4))) float f32x4;
typedef __attribute__((ext_vector_type(2))) unsigned int uint2v;

#define S_LEN 4096
#define NBATCH 2
#define DMODEL 768
#define NH 12
#define HD 64
#define MROWS (S_LEN * NBATCH)   // 8192

__device__ __forceinline__ unsigned short f2bf(float f) {
    unsigned int u = __builtin_bit_cast(unsigned int, f);
    u += 0x7fffu + ((u >> 16) & 1u);       // round-to-nearest-even
    return (unsigned short)(u >> 16);
}

// async global->LDS, 16B per lane; LDS dst = wave-uniform base + lane*16,
// global src is PER-LANE.
#define GLDS16(gp, lp) __builtin_amdgcn_global_load_lds( \
    (const __attribute__((address_space(1))) void*)(gp), \
    (__attribute__((address_space(3))) void*)(lp), 16, 0, 0)

#define MFMA_BF16 __builtin_amdgcn_mfma_f32_16x16x32_bf16

// -------- kernel 1: fused input cvt --------
// blocks [0, 6144): val fp32 -> X bf16 (8192x768, 4 elems/thread)
// blocks [6144, 7008): W fp32 (K x N) -> WT bf16 (z-major, [nf][k])
__global__ __launch_bounds__(256) void cvt_all_kernel(
    const float* __restrict__ val, const float* __restrict__ Wq,
    const float* __restrict__ Wk,  const float* __restrict__ Wv,
    short* __restrict__ X, short* __restrict__ WT) {
    const int bid = blockIdx.x;
    if (bid < 6144) {
        size_t i = (size_t)bid * 256 + threadIdx.x;
        const f32x4 v = *(const f32x4*)(val + i * 4);
        short4v o;
        o.x = (short)f2bf(v.x); o.y = (short)f2bf(v.y);
        o.z = (short)f2bf(v.z); o.w = (short)f2bf(v.w);
        *(short4v*)(X + i * 4) = o;
    } else {
        const int id = bid - 6144;            // 864 = 3 z * 96 k-blk * 3 n-blk
        const int z  = id / 288;
        const int k0 = ((id % 288) / 3) * 8;
        const int n  = (id % 3) * 256 + threadIdx.x;
        const float* W = (z == 0) ? Wq : ((z == 1) ? Wk : Wv);
        short8 o;
#pragma unroll
        for (int i = 0; i < 8; ++i)
            o[i] = (short)f2bf(W[(size_t)(k0 + i) * DMODEL + n]);
        *(short8*)(WT + (size_t)z * DMODEL * DMODEL + (size_t)n * DMODEL + k0) = o;
    }
}

// ------- kernel 2: fused QKV GEMM, 128x192 tile, 4 waves, wave tile 64x96 -------
// acc 4x6, 2-buffer 2-barrier counted-vmcnt (5 loads per STAGE -> vmcnt(5)),
// 3 blocks/CU. z==2 written transposed ([bh][e][s]).
#define NT 24   // 768/32 K-steps
__global__ __launch_bounds__(256, 3) void gemm_qkv_kernel(
    const short* __restrict__ X, const short* __restrict__ WT,
    const float* __restrict__ bq, const float* __restrict__ bk, const float* __restrict__ bv,
    short* __restrict__ Q, short* __restrict__ K, short* __restrict__ Vt)
{
    __shared__ __align__(16) short SMEM[26112];  // 51KB: stage A[2][4096]|B[2][6144]; C reuse
    short* As = SMEM;            // 2 * 4096 shorts
    short* Bs = SMEM + 8192;     // 2 * 6144 shorts

    const int phys = blockIdx.x;                 // 768 = 8 XCD * (8 m * 12 n), n-fastest
    const int xcd = phys & 7, ii = phys >> 3;
    const int m0  = (xcd * 8 + ii / 12) * 128;
    const int nf  = (ii % 12) * 192;
    const int z   = nf / DMODEL;                 // 4 n-tiles per z (exact boundaries)
    const int n0w = nf - z * DMODEL;

    const int tid = threadIdx.x, lane = tid & 63, wid = tid >> 6;
    const int wm = wid >> 1, wn = wid & 1;       // 2M x 2N waves, wave tile 64x96
    const int fr = lane & 15, kg = lane >> 4;
    const int wr = wm * 64, wc = wn * 96;

    const float* bias = (z == 0) ? bq : ((z == 1) ? bk : bv);
    short*       OUT  = (z == 0) ? Q  : ((z == 1) ? K  : Vt);

    f32x4 acc[4][6];
#pragma unroll
    for (int i = 0; i < 4; ++i)
#pragma unroll
        for (int j = 0; j < 6; ++j) acc[i][j] = (f32x4){0.f, 0.f, 0.f, 0.f};

    const int gslot = (lane & 3) ^ ((lane >> 3) & 3);
    const short* srcA = X  + (size_t)(m0 + wid * 32 + (lane >> 2)) * DMODEL + gslot * 8;
    const short* srcB = WT + (size_t)(nf + wid * 48 + (lane >> 2)) * DMODEL + gslot * 8;

#define STAGE(buf, kt) do { \
        GLDS16(srcA + (kt),               As + (buf) * 4096 + wid * 1024);        \
        GLDS16(srcA + (kt) + 16 * DMODEL, As + (buf) * 4096 + wid * 1024 + 512);  \
        GLDS16(srcB + (kt),               Bs + (buf) * 6144 + wid * 1536);        \
        GLDS16(srcB + (kt) + 16 * DMODEL, Bs + (buf) * 6144 + wid * 1536 + 512);  \
        GLDS16(srcB + (kt) + 32 * DMODEL, Bs + (buf) * 6144 + wid * 1536 + 1024); \
    } while (0)

    STAGE(0, 0);
    STAGE(1, 32);
    asm volatile("s_waitcnt vmcnt(5)" ::: "memory");   // tile0 (5 loads) done; tile1 in flight
    __builtin_amdgcn_sched_barrier(0);
    __builtin_amdgcn_s_barrier();

    const int rslot = (fr >> 1) & 3;             // read-side swizzle (same involution)
    for (int t = 0; t < NT; ++t) {
        const short* Ab = As + (t & 1) * 4096;
        const short* Bb = Bs + (t & 1) * 6144;
        short8 af[4], bfv[6];
#pragma unroll
        for (int mi = 0; mi < 4; ++mi)
            af[mi] = *(const short8*)(Ab + (wr + mi * 16 + fr) * 32 + (kg ^ rslot) * 8);
#pragma unroll
        for (int nj = 0; nj < 6; ++nj)
            bfv[nj] = *(const short8*)(Bb + (wc + nj * 16 + fr) * 32 + (kg ^ rslot) * 8);
        asm volatile("s_waitcnt lgkmcnt(0)" ::: "memory");   // my reads done
        __builtin_amdgcn_sched_barrier(0);
        __builtin_amdgcn_s_barrier();            // B1: ALL waves' reads of buf[t&1] done
        __builtin_amdgcn_sched_barrier(0);
        if (t + 2 < NT) STAGE(t & 1, (t + 2) * 32);          // WAR-safe overwrite
        __builtin_amdgcn_sched_barrier(0);

        __builtin_amdgcn_s_setprio(1);           // MFMA hides glds issue + latency
#pragma unroll
        for (int mi = 0; mi < 4; ++mi)
#pragma unroll
            for (int nj = 0; nj < 6; ++nj)
                acc[mi][nj] = MFMA_BF16(af[mi], bfv[nj], acc[mi][nj], 0, 0, 0);
        __builtin_amdgcn_s_setprio(0);

        // counted gate: wait tile t+1 (5 oldest); leave tile t+2's 5 in flight
        if (t + 2 < NT) { asm volatile("s_waitcnt vmcnt(5)" ::: "memory"); }
        else            { asm volatile("s_waitcnt vmcnt(0)" ::: "memory"); }
        __builtin_amdgcn_sched_barrier(0);
        __builtin_amdgcn_s_barrier();            // B2: tile t+1 visible to all waves
    }
#undef STAGE

    const float scale = (z == 0) ? 0.18033688f : 1.0f;  // q: 1/sqrt(64) * log2(e)
    float bval[6];
#pragma unroll
    for (int nj = 0; nj < 6; ++nj) bval[nj] = bias[n0w + wc + nj * 16 + fr];

    if (z < 2) {                            // Q/K: [bh][s][e], coalesced short8
        short* Cs = SMEM;                   // [128][200] bf16 (25600 <= 26112)
#pragma unroll
        for (int mi = 0; mi < 4; ++mi)
#pragma unroll
            for (int nj = 0; nj < 6; ++nj)
#pragma unroll
                for (int r = 0; r < 4; ++r)
                    Cs[(wr + mi * 16 + 4 * kg + r) * 200 + (wc + nj * 16 + fr)] =
                        (short)f2bf((acc[mi][nj][r] + bval[nj]) * scale);
        __syncthreads();
#pragma unroll
        for (int it = 0; it < 12; ++it) {   // 3072 chunks of 8 elems
            const int flat = it * 256 + tid;
            const int row = flat / 24, c8 = (flat % 24) * 8;
            const int gm = m0 + row, gn = n0w + c8;
            const int s = gm >> 1, bb = gm & 1, hh = gn >> 6, e0 = gn & 63;
            *(short8*)(&OUT[((size_t)(bb * NH + hh) * S_LEN + s) * HD + e0]) =
                *(const short8*)(&Cs[row * 200 + c8]);
        }
    } else {                                // V: write transposed [bh][e][s]
        short* Ct = SMEM;                   // [192 cols][136]: b-deinterleaved rows
#pragma unroll
        for (int mi = 0; mi < 4; ++mi)
#pragma unroll
            for (int nj = 0; nj < 6; ++nj)
#pragma unroll
                for (int r = 0; r < 4; ++r) {
                    const int row = wr + mi * 16 + 4 * kg + r;
                    const int col = wc + nj * 16 + fr;
                    Ct[col * 136 + (row & 1) * 68 + (row >> 1)] =
                        (short)f2bf(acc[mi][nj][r] + bval[nj]);
                }
        __syncthreads();
#pragma unroll
        for (int it = 0; it < 12; ++it) {   // 8B-aligned LDS reads, coalesced stores
            const int flat = it * 256 + tid;
            const int col = flat >> 4;              // 0..191
            const int b   = (flat >> 3) & 1;
            const int sc  = flat & 7;               // 8-s chunk
            const short* base = &Ct[col * 136 + b * 68 + sc * 8];
            short8 v;
            *(short4v*)&v      = *(const short4v*)(base);
            *((short4v*)&v + 1) = *(const short4v*)(base + 4);
            const int e = col & 63, hl = col >> 6;
            const int bh = b * NH + (n0w >> 6) + hl;
            *(short8*)(&OUT[(size_t)bh * HD * S_LEN + (size_t)e * S_LEN
                            + (m0 >> 1) + sc * 8]) = v;
        }
    }
}

// ------- kernel 3: flash banded attention: block = (bh, 128 q), 3 kv-tiles dbuf -------
// (R18 attention, byte-identical: flash structure + T13 defer-max.)
#define PCST  40

__global__ __launch_bounds__(512, 4) void attn_kernel(
    const short* __restrict__ Q, const short* __restrict__ K,
    const short* __restrict__ Vt, float* __restrict__ out)
{
    __shared__ __align__(16) short KS[2 * 8192];       // 32 KB (2 slots)
    __shared__ __align__(16) short VS[2 * 8192];       // 32 KB
    __shared__ __align__(16) short Pc[8][16 * PCST];   // 10 KB

    const int tid = threadIdx.x, lane = tid & 63, w = tid >> 6;
    const int id = blockIdx.x;                   // 768 blocks; XCD owns 3 heads
    const int logical = (id & 7) * 96 + (id >> 3);
    const int bx = logical & 31;                 // q-tile index (128 q)
    const int bh = logical >> 5;                 // batch*head
    const int bb = bh / NH, hh = bh % NH;
    const int fr = lane & 15, g = lane >> 4;
    const int q0 = bx * 128;
    const int kstart = q0 - 256;
    const int e0m = fr - 4 * g;

    const short* Qb = Q  + (size_t)bh * S_LEN * HD;
    const short* Kb = K  + (size_t)bh * S_LEN * HD;
    const short* Vb = Vt + (size_t)bh * HD * S_LEN;

#define STAGESEG(slot, kb) do {                                                \
        const int _kc = (kb) < 0 ? 0 : (kb);                                   \
        _Pragma("unroll")                                                      \
        for (int _j = 0; _j < 2; ++_j) {  /* K [128row][8ch], swz ch^row&7 */  \
            const int _p = _j * 512 + tid;                                     \
            const int _row = _p >> 3, _ch = _p & 7;                            \
            GLDS16(Kb + (size_t)(_kc * 128 + _row) * HD + (_ch ^ (_row & 7)) * 8, \
                   KS + (slot) * 8192 + _p * 8);                               \
        }                                                                      \
        _Pragma("unroll")                                                      \
        for (int _j = 0; _j < 2; ++_j) {  /* V [64e][16ch], swz ch^e&7 */      \
            const int _p = _j * 512 + tid;                                     \
            const int _e = _p >> 4, _ch = _p & 15;                             \
            GLDS16(Vb + (size_t)_e * S_LEN + _kc * 128 + ((_ch ^ (_e & 7)) * 8), \
                   VS + (slot) * 8192 + _p * 8);                               \
        }                                                                      \
    } while (0)

    // ---- Q fragments first (oldest in vmcnt queue, drained by prologue wait) ----
    const int qrow = q0 + w * 16 + fr;
    const short8 qa0 = *(const short8*)(Qb + (size_t)qrow * HD + g * 8);
    const short8 qa1 = *(const short8*)(Qb + (size_t)qrow * HD + 32 + g * 8);

    const int kb0 = bx - 2;                      // first kv-tile index
    STAGESEG(0, kb0);
    STAGESEG(1, kb0 + 1);
    asm volatile("s_waitcnt vmcnt(4)" ::: "memory");   // Q + tile0 done; tile1 in flight
    __builtin_amdgcn_sched_barrier(0);
    __builtin_amdgcn_s_barrier();

    const bool interior = (kstart >= 0);
    float m = -1e30f, l = 0.f;
    f32x4 o[4];
#pragma unroll
    for (int et = 0; et < 4; ++et) o[et] = (f32x4){0.f, 0.f, 0.f, 0.f};

#pragma unroll
    for (int c = 0; c < 3; ++c) {
        const int slot = c & 1;
        const short* Kt = KS + slot * 8192;
        const short* Vtile = VS + slot * 8192;

        // ---- QK^T on this tile's 8 subtiles (active: u in [0,16]) ----
        float sc[8][4];
        unsigned int pk[8][2];
#pragma unroll
        for (int s = 0; s < 8; ++s) {
            const int u = 8 * c + s - w;             // wave-uniform
            if (u >= 0 && u <= 16) {
                const int row = s * 16 + fr;
                const short* kb8 = Kt + row * 64;
                const short8 a0 = *(const short8*)(kb8 + (g ^ (fr & 7)) * 8);
                const short8 a1 = *(const short8*)(kb8 + ((4 + g) ^ (fr & 7)) * 8);
                f32x4 d = {0.f, 0.f, 0.f, 0.f};
                d = MFMA_BF16(a0, qa0, d, 0, 0, 0);
                d = MFMA_BF16(a1, qa1, d, 0, 0, 0);
                if (interior) {
                    if (u == 0) {
#pragma unroll
                        for (int r = 0; r < 4; ++r) sc[s][r] = (e0m <= r) ? d[r] : -3e38f;
                    } else if (u == 16) {
#pragma unroll
                        for (int r = 0; r < 4; ++r) sc[s][r] = (e0m >= r) ? d[r] : -3e38f;
                    } else {
#pragma unroll
                        for (int r = 0; r < 4; ++r) sc[s][r] = d[r];
                    }
                } else {
                    const int gk0 = kstart + (8 * c + s) * 16 + 4 * g;
#pragma unroll
                    for (int r = 0; r < 4; ++r) {
                        const int dd = 256 + fr - 16 * u - 4 * g - r;
                        const bool ok = (dd >= 0) & (dd <= 256) & (gk0 + r >= 0);
                        sc[s][r] = ok ? d[r] : -3e38f;
                    }
                }
            } else {
#pragma unroll
                for (int r = 0; r < 4; ++r) sc[s][r] = -3e38f;
            }
        }

        // ---- online softmax update (T13 defer-max) ----
        float tm[8];
#pragma unroll
        for (int s = 0; s < 8; ++s)
            tm[s] = fmaxf(fmaxf(sc[s][0], sc[s][1]), fmaxf(sc[s][2], sc[s][3]));
#pragma unroll
        for (int st = 1; st < 8; st <<= 1)
#pragma unroll
            for (int i = 0; i + st < 8; i += 2 * st) tm[i] = fmaxf(tm[i], tm[i + st]);
        float tmax = fmaxf(tm[0], __shfl_xor(tm[0], 16));
        tmax = fmaxf(tmax, __shfl_xor(tmax, 32));

        if (!__all(tmax - m <= 11.5f)) {         // rescale only when max grows
            const float nm = fmaxf(m, tmax);
            const float esc = exp2f(m - nm);     // scale for query fr
            float es4[4];
#pragma unroll
            for (int r = 0; r < 4; ++r) es4[r] = __shfl(esc, 4 * g + r);
#pragma unroll
            for (int et = 0; et < 4; ++et)
#pragma unroll
                for (int r = 0; r < 4; ++r) o[et][r] *= es4[r];
            l *= esc;
            m = nm;
        }

#pragma unroll
        for (int s = 0; s < 8; ++s)
#pragma unroll
            for (int r = 0; r < 4; ++r) sc[s][r] = exp2f(sc[s][r] - m);
        float ts[8];
#pragma unroll
        for (int s = 0; s < 8; ++s)
            ts[s] = (sc[s][0] + sc[s][1]) + (sc[s][2] + sc[s][3]);
#pragma unroll
        for (int st = 1; st < 8; st <<= 1)
#pragma unroll
            for (int i = 0; i + st < 8; i += 2 * st) ts[i] += ts[i + st];
        float tsum = ts[0] + __shfl_xor(ts[0], 16);
        tsum += __shfl_xor(tsum, 32);
        l += tsum;

#pragma unroll
        for (int s = 0; s < 8; ++s) {
            pk[s][0] = (unsigned)f2bf(sc[s][0]) | ((unsigned)f2bf(sc[s][1]) << 16);
            pk[s][1] = (unsigned)f2bf(sc[s][2]) | ((unsigned)f2bf(sc[s][3]) << 16);
        }

        // ---- PV on active 32-key chunks ----
        short* pb = &Pc[w][0];
#pragma unroll
        for (int i = 0; i < 4; ++i) {
            const int slo = 8 * c + 2 * i, shi = slo + 1;   // global subtiles
            if (shi >= w && slo <= w + 16) {                // wave-uniform
                *(uint2v*)(pb + fr * PCST + 4 * g)      = (uint2v){pk[2 * i][0], pk[2 * i][1]};
                *(uint2v*)(pb + fr * PCST + 16 + 4 * g) = (uint2v){pk[2 * i + 1][0], pk[2 * i + 1][1]};
                const short8 pa = *(const short8*)(pb + fr * PCST + 8 * g);
                const int lc = 4 * i + g;                   // logical V chunk in tile
                const short* vb8 = Vtile + fr * 128 + ((lc ^ (fr & 7)) * 8);
                __builtin_amdgcn_s_setprio(1);
#pragma unroll
                for (int et = 0; et < 4; ++et) {
                    const short8 vb = *(const short8*)(vb8 + et * 2048);
                    o[et] = MFMA_BF16(pa, vb, o[et], 0, 0, 0);
                }
                __builtin_amdgcn_s_setprio(0);
            }
        }

        // ---- stage tile c+2 into this slot; ensure tile c+1 landed ----
        if (c == 0) {
            __builtin_amdgcn_s_barrier();            // all waves done with slot 0
            STAGESEG(0, kb0 + 2);
            asm volatile("s_waitcnt vmcnt(4)" ::: "memory");   // tile1 landed
            __builtin_amdgcn_sched_barrier(0);
            __builtin_amdgcn_s_barrier();
        } else if (c == 1) {
            __builtin_amdgcn_s_barrier();
            asm volatile("s_waitcnt vmcnt(0)" ::: "memory");   // tile2 landed
            __builtin_amdgcn_sched_barrier(0);
            __builtin_amdgcn_s_barrier();
        }
    }
#undef STAGESEG

    const float inv = 1.0f / l;                    // valid for query = fr
    float inv4[4];
#pragma unroll
    for (int r = 0; r < 4; ++r) inv4[r] = __shfl(inv, 4 * g + r);

#pragma unroll
    for (int et = 0; et < 4; ++et)
#pragma unroll
        for (int r = 0; r < 4; ++r) {
            const int qi = q0 + w * 16 + 4 * g + r;
            const int dd = hh * HD + et * 16 + fr;
            out[((size_t)qi * NBATCH + bb) * DMODEL + dd] = o[et][r] * inv4[r];
        }
}

extern "C" void kernel_launch(void* const* d_in, const int* in_sizes, int n_in,
                              void* d_out, int out_size, void* d_ws, size_t ws_size,
                              hipStream_t stream) {
    (void)in_sizes; (void)n_in; (void)out_size; (void)ws_size;
    const float* val = (const float*)d_in[0];
    const float* Wq  = (const float*)d_in[1];
    const float* bq  = (const float*)d_in[2];
    const float* Wk  = (const float*)d_in[3];
    const float* bk  = (const float*)d_in[4];
    const float* Wv  = (const float*)d_in[5];
    const float* bv  = (const float*)d_in[6];
    float* out = (float*)d_out;

    char* ws = (char*)d_ws;
    const size_t SZ_X  = (size_t)MROWS * DMODEL * 2;
    const size_t SZ_W  = (size_t)DMODEL * DMODEL * 2;
    short* X  = (short*)(ws);
    short* WT = (short*)(ws + SZ_X);
    short* Qb = (short*)(ws + SZ_X + 3 * SZ_W);
    short* Kb = (short*)(ws + SZ_X + 3 * SZ_W + SZ_X);
    short* Vt = (short*)(ws + SZ_X + 3 * SZ_W + 2 * SZ_X);

    cvt_all_kernel<<<dim3(7008), dim3(256), 0, stream>>>(val, Wq, Wk, Wv, X, WT);
    gemm_qkv_kernel<<<dim3(768), dim3(256), 0, stream>>>(
        X, WT, bq, bk, bv, Qb, Kb, Vt);
    attn_kernel<<<dim3(768), dim3(512), 0, stream>>>(Qb, Kb, Vt, out);
}

// Round 21
// 76.274 us; speedup vs baseline: 1.9678x; 1.0076x over previous
//
#include <hip/hip_runtime.h>
#include <stdint.h>

typedef __attribute__((ext_vector_type(8))) short short8;
typedef __attribute__((ext_vector_type(4))) short short4v;
typedef __attribute__((ext_vector_type(4))) float f32x4;
typedef __attribute__((ext_vector_type(2))) unsigned int uint2v;

#define S_LEN 4096
#define NBATCH 2
#define DMODEL 768
#define NH 12
#define HD 64
#define MROWS (S_LEN * NBATCH)   // 8192

__device__ __forceinline__ unsigned short f2bf(float f) {
    unsigned int u = __builtin_bit_cast(unsigned int, f);
    u += 0x7fffu + ((u >> 16) & 1u);       // round-to-nearest-even
    return (unsigned short)(u >> 16);
}

// async global->LDS, 16B per lane; LDS dst = wave-uniform base + lane*16,
// global src is PER-LANE.
#define GLDS16(gp, lp) __builtin_amdgcn_global_load_lds( \
    (const __attribute__((address_space(1))) void*)(gp), \
    (__attribute__((address_space(3))) void*)(lp), 16, 0, 0)

#define MFMA_BF16 __builtin_amdgcn_mfma_f32_16x16x32_bf16

// -------- kernel 1: fused input cvt --------
// blocks [0, 6144): val fp32 -> X bf16 (8192x768, 4 elems/thread)
// blocks [6144, 7008): W fp32 (K x N) -> WT bf16 (z-major, [nf][k])
__global__ __launch_bounds__(256) void cvt_all_kernel(
    const float* __restrict__ val, const float* __restrict__ Wq,
    const float* __restrict__ Wk,  const float* __restrict__ Wv,
    short* __restrict__ X, short* __restrict__ WT) {
    const int bid = blockIdx.x;
    if (bid < 6144) {
        size_t i = (size_t)bid * 256 + threadIdx.x;
        const f32x4 v = *(const f32x4*)(val + i * 4);
        short4v o;
        o.x = (short)f2bf(v.x); o.y = (short)f2bf(v.y);
        o.z = (short)f2bf(v.z); o.w = (short)f2bf(v.w);
        *(short4v*)(X + i * 4) = o;
    } else {
        const int id = bid - 6144;            // 864 = 3 z * 96 k-blk * 3 n-blk
        const int z  = id / 288;
        const int k0 = ((id % 288) / 3) * 8;
        const int n  = (id % 3) * 256 + threadIdx.x;
        const float* W = (z == 0) ? Wq : ((z == 1) ? Wk : Wv);
        short8 o;
#pragma unroll
        for (int i = 0; i < 8; ++i)
            o[i] = (short)f2bf(W[(size_t)(k0 + i) * DMODEL + n]);
        *(short8*)(WT + (size_t)z * DMODEL * DMODEL + (size_t)n * DMODEL + k0) = o;
    }
}

// ------- kernel 2: fused QKV GEMM, 128x192 tile, 4 waves, wave tile 64x96 -------
// acc 4x6, 2-buffer 2-barrier counted-vmcnt (5 loads per STAGE -> vmcnt(5)),
// 3 blocks/CU. z==2 written transposed ([bh][e][s]).
#define NT 24   // 768/32 K-steps
__global__ __launch_bounds__(256, 3) void gemm_qkv_kernel(
    const short* __restrict__ X, const short* __restrict__ WT,
    const float* __restrict__ bq, const float* __restrict__ bk, const float* __restrict__ bv,
    short* __restrict__ Q, short* __restrict__ K, short* __restrict__ Vt)
{
    __shared__ __align__(16) short SMEM[26112];  // 51KB: stage A[2][4096]|B[2][6144]; C reuse
    short* As = SMEM;            // 2 * 4096 shorts
    short* Bs = SMEM + 8192;     // 2 * 6144 shorts

    const int phys = blockIdx.x;                 // 768 = 8 XCD * (8 m * 12 n), n-fastest
    const int xcd = phys & 7, ii = phys >> 3;
    const int m0  = (xcd * 8 + ii / 12) * 128;
    const int nf  = (ii % 12) * 192;
    const int z   = nf / DMODEL;                 // 4 n-tiles per z (exact boundaries)
    const int n0w = nf - z * DMODEL;

    const int tid = threadIdx.x, lane = tid & 63, wid = tid >> 6;
    const int wm = wid >> 1, wn = wid & 1;       // 2M x 2N waves, wave tile 64x96
    const int fr = lane & 15, kg = lane >> 4;
    const int wr = wm * 64, wc = wn * 96;

    const float* bias = (z == 0) ? bq : ((z == 1) ? bk : bv);
    short*       OUT  = (z == 0) ? Q  : ((z == 1) ? K  : Vt);

    f32x4 acc[4][6];
#pragma unroll
    for (int i = 0; i < 4; ++i)
#pragma unroll
        for (int j = 0; j < 6; ++j) acc[i][j] = (f32x4){0.f, 0.f, 0.f, 0.f};

    const int gslot = (lane & 3) ^ ((lane >> 3) & 3);
    const short* srcA = X  + (size_t)(m0 + wid * 32 + (lane >> 2)) * DMODEL + gslot * 8;
    const short* srcB = WT + (size_t)(nf + wid * 48 + (lane >> 2)) * DMODEL + gslot * 8;

#define STAGE(buf, kt) do { \
        GLDS16(srcA + (kt),               As + (buf) * 4096 + wid * 1024);        \
        GLDS16(srcA + (kt) + 16 * DMODEL, As + (buf) * 4096 + wid * 1024 + 512);  \
        GLDS16(srcB + (kt),               Bs + (buf) * 6144 + wid * 1536);        \
        GLDS16(srcB + (kt) + 16 * DMODEL, Bs + (buf) * 6144 + wid * 1536 + 512);  \
        GLDS16(srcB + (kt) + 32 * DMODEL, Bs + (buf) * 6144 + wid * 1536 + 1024); \
    } while (0)

    STAGE(0, 0);
    STAGE(1, 32);
    asm volatile("s_waitcnt vmcnt(5)" ::: "memory");   // tile0 (5 loads) done; tile1 in flight
    __builtin_amdgcn_sched_barrier(0);
    __builtin_amdgcn_s_barrier();

    const int rslot = (fr >> 1) & 3;             // read-side swizzle (same involution)
    for (int t = 0; t < NT; ++t) {
        const short* Ab = As + (t & 1) * 4096;
        const short* Bb = Bs + (t & 1) * 6144;
        short8 af[4], bfv[6];
#pragma unroll
        for (int mi = 0; mi < 4; ++mi)
            af[mi] = *(const short8*)(Ab + (wr + mi * 16 + fr) * 32 + (kg ^ rslot) * 8);
#pragma unroll
        for (int nj = 0; nj < 6; ++nj)
            bfv[nj] = *(const short8*)(Bb + (wc + nj * 16 + fr) * 32 + (kg ^ rslot) * 8);
        asm volatile("s_waitcnt lgkmcnt(0)" ::: "memory");   // my reads done
        __builtin_amdgcn_sched_barrier(0);
        __builtin_amdgcn_s_barrier();            // B1: ALL waves' reads of buf[t&1] done
        __builtin_amdgcn_sched_barrier(0);
        if (t + 2 < NT) STAGE(t & 1, (t + 2) * 32);          // WAR-safe overwrite
        __builtin_amdgcn_sched_barrier(0);

        __builtin_amdgcn_s_setprio(1);           // MFMA hides glds issue + latency
#pragma unroll
        for (int mi = 0; mi < 4; ++mi)
#pragma unroll
            for (int nj = 0; nj < 6; ++nj)
                acc[mi][nj] = MFMA_BF16(af[mi], bfv[nj], acc[mi][nj], 0, 0, 0);
        __builtin_amdgcn_s_setprio(0);

        // counted gate: wait tile t+1 (5 oldest); leave tile t+2's 5 in flight
        if (t + 2 < NT) { asm volatile("s_waitcnt vmcnt(5)" ::: "memory"); }
        else            { asm volatile("s_waitcnt vmcnt(0)" ::: "memory"); }
        __builtin_amdgcn_sched_barrier(0);
        __builtin_amdgcn_s_barrier();            // B2: tile t+1 visible to all waves
    }
#undef STAGE

    const float scale = (z == 0) ? 0.18033688f : 1.0f;  // q: 1/sqrt(64) * log2(e)
    float bval[6];
#pragma unroll
    for (int nj = 0; nj < 6; ++nj) bval[nj] = bias[n0w + wc + nj * 16 + fr];

    if (z < 2) {                            // Q/K: [bh][s][e], coalesced short8
        short* Cs = SMEM;                   // [128][200] bf16 (25600 <= 26112)
#pragma unroll
        for (int mi = 0; mi < 4; ++mi)
#pragma unroll
            for (int nj = 0; nj < 6; ++nj)
#pragma unroll
                for (int r = 0; r < 4; ++r)
                    Cs[(wr + mi * 16 + 4 * kg + r) * 200 + (wc + nj * 16 + fr)] =
                        (short)f2bf((acc[mi][nj][r] + bval[nj]) * scale);
        __syncthreads();
#pragma unroll
        for (int it = 0; it < 12; ++it) {   // 3072 chunks of 8 elems
            const int flat = it * 256 + tid;
            const int row = flat / 24, c8 = (flat % 24) * 8;
            const int gm = m0 + row, gn = n0w + c8;
            const int s = gm >> 1, bb = gm & 1, hh = gn >> 6, e0 = gn & 63;
            *(short8*)(&OUT[((size_t)(bb * NH + hh) * S_LEN + s) * HD + e0]) =
                *(const short8*)(&Cs[row * 200 + c8]);
        }
    } else {                                // V: write transposed [bh][e][s]
        short* Ct = SMEM;                   // [192 cols][136]: b-deinterleaved rows
#pragma unroll
        for (int mi = 0; mi < 4; ++mi)
#pragma unroll
            for (int nj = 0; nj < 6; ++nj)
#pragma unroll
                for (int r = 0; r < 4; ++r) {
                    const int row = wr + mi * 16 + 4 * kg + r;
                    const int col = wc + nj * 16 + fr;
                    Ct[col * 136 + (row & 1) * 68 + (row >> 1)] =
                        (short)f2bf(acc[mi][nj][r] + bval[nj]);
                }
        __syncthreads();
#pragma unroll
        for (int it = 0; it < 12; ++it) {   // 8B-aligned LDS reads, coalesced stores
            const int flat = it * 256 + tid;
            const int col = flat >> 4;              // 0..191
            const int b   = (flat >> 3) & 1;
            const int sc  = flat & 7;               // 8-s chunk
            const short* base = &Ct[col * 136 + b * 68 + sc * 8];
            short8 v;
            *(short4v*)&v      = *(const short4v*)(base);
            *((short4v*)&v + 1) = *(const short4v*)(base + 4);
            const int e = col & 63, hl = col >> 6;
            const int bh = b * NH + (n0w >> 6) + hl;
            *(short8*)(&OUT[(size_t)bh * HD * S_LEN + (size_t)e * S_LEN
                            + (m0 >> 1) + sc * 8]) = v;
        }
    }
}

// ------- kernel 3: flash banded attention, 64-key kv-tiles, 3 blocks/CU -------
// 6 tiles of 64 keys, 2-slot dbuf; LDS 42 KB -> 3 blocks/CU = 768 blocks in ONE
// full round (was 1.5 rounds at 2/CU). Same math as R18/R20: subtile st = 4c+s,
// active iff st-w in [0,16]; T13 defer-max; per-wave LDS P round-trip.
#define PCST  40

__global__ __launch_bounds__(512, 6) void attn_kernel(
    const short* __restrict__ Q, const short* __restrict__ K,
    const short* __restrict__ Vt, float* __restrict__ out)
{
    __shared__ __align__(16) short KS[2 * 4096];       // 16 KB (2 slots, 64 keys x 64 e)
    __shared__ __align__(16) short VS[2 * 4096];       // 16 KB (2 slots, 64 e x 64 keys)
    __shared__ __align__(16) short Pc[8][16 * PCST];   // 10 KB

    const int tid = threadIdx.x, lane = tid & 63, w = tid >> 6;
    const int id = blockIdx.x;                   // 768 blocks; XCD owns 3 heads
    const int logical = (id & 7) * 96 + (id >> 3);
    const int bx = logical & 31;                 // q-tile index (128 q)
    const int bh = logical >> 5;                 // batch*head
    const int bb = bh / NH, hh = bh % NH;
    const int fr = lane & 15, g = lane >> 4;
    const int q0 = bx * 128;
    const int kstart = q0 - 256;
    const int e0m = fr - 4 * g;

    const short* Qb = Q  + (size_t)bh * S_LEN * HD;
    const short* Kb = K  + (size_t)bh * S_LEN * HD;
    const short* Vb = Vt + (size_t)bh * HD * S_LEN;

    // 64-key segment: K [64row][8ch16B] swz ch^(row&7); V [64e][8ch] swz ch^(e&7)
#define STAGESEG(slot, kb) do {                                                \
        const int _kc = (kb) < 0 ? 0 : (kb);                                   \
        {   /* K: 1 load/thread */                                             \
            const int _row = tid >> 3, _ch = tid & 7;                          \
            GLDS16(Kb + (size_t)(_kc * 64 + _row) * HD + ((_ch ^ (_row & 7)) * 8), \
                   KS + (slot) * 4096 + tid * 8);                              \
        }                                                                      \
        {   /* V: 1 load/thread */                                             \
            const int _e = tid >> 3, _ch = tid & 7;                            \
            GLDS16(Vb + (size_t)_e * S_LEN + _kc * 64 + ((_ch ^ (_e & 7)) * 8), \
                   VS + (slot) * 4096 + tid * 8);                              \
        }                                                                      \
    } while (0)

    // ---- Q fragments first (oldest in vmcnt queue) ----
    const int qrow = q0 + w * 16 + fr;
    const short8 qa0 = *(const short8*)(Qb + (size_t)qrow * HD + g * 8);
    const short8 qa1 = *(const short8*)(Qb + (size_t)qrow * HD + 32 + g * 8);

    const int kb0 = 2 * bx - 4;                  // first 64-key tile index
    STAGESEG(0, kb0);
    STAGESEG(1, kb0 + 1);
    asm volatile("s_waitcnt vmcnt(2)" ::: "memory");   // Q + tile0 done; tile1 in flight
    __builtin_amdgcn_sched_barrier(0);
    __builtin_amdgcn_s_barrier();

    const bool interior = (kstart >= 0);
    float m = -1e30f, l = 0.f;
    f32x4 o[4];
#pragma unroll
    for (int et = 0; et < 4; ++et) o[et] = (f32x4){0.f, 0.f, 0.f, 0.f};

#pragma unroll
    for (int c = 0; c < 6; ++c) {
        const int slot = c & 1;
        const short* Kt = KS + slot * 4096;
        const short* Vtile = VS + slot * 4096;

        // ---- QK^T on this tile's 4 subtiles (active: u in [0,16]) ----
        float sc[4][4];
        unsigned int pk[4][2];
#pragma unroll
        for (int s = 0; s < 4; ++s) {
            const int u = 4 * c + s - w;             // wave-uniform
            if (u >= 0 && u <= 16) {
                const int row = s * 16 + fr;
                const short* kb8 = Kt + row * 64;
                const short8 a0 = *(const short8*)(kb8 + (g ^ (fr & 7)) * 8);
                const short8 a1 = *(const short8*)(kb8 + ((4 + g) ^ (fr & 7)) * 8);
                f32x4 d = {0.f, 0.f, 0.f, 0.f};
                d = MFMA_BF16(a0, qa0, d, 0, 0, 0);
                d = MFMA_BF16(a1, qa1, d, 0, 0, 0);
                if (interior) {
                    if (u == 0) {
#pragma unroll
                        for (int r = 0; r < 4; ++r) sc[s][r] = (e0m <= r) ? d[r] : -3e38f;
                    } else if (u == 16) {
#pragma unroll
                        for (int r = 0; r < 4; ++r) sc[s][r] = (e0m >= r) ? d[r] : -3e38f;
                    } else {
#pragma unroll
                        for (int r = 0; r < 4; ++r) sc[s][r] = d[r];
                    }
                } else {
                    const int gk0 = kstart + (4 * c + s) * 16 + 4 * g;
#pragma unroll
                    for (int r = 0; r < 4; ++r) {
                        const int dd = 256 + fr - 16 * u - 4 * g - r;
                        const bool ok = (dd >= 0) & (dd <= 256) & (gk0 + r >= 0);
                        sc[s][r] = ok ? d[r] : -3e38f;
                    }
                }
            } else {
#pragma unroll
                for (int r = 0; r < 4; ++r) sc[s][r] = -3e38f;
            }
        }

        // ---- online softmax update (T13 defer-max) ----
        float tm[4];
#pragma unroll
        for (int s = 0; s < 4; ++s)
            tm[s] = fmaxf(fmaxf(sc[s][0], sc[s][1]), fmaxf(sc[s][2], sc[s][3]));
        float tmax = fmaxf(fmaxf(tm[0], tm[1]), fmaxf(tm[2], tm[3]));
        tmax = fmaxf(tmax, __shfl_xor(tmax, 16));
        tmax = fmaxf(tmax, __shfl_xor(tmax, 32));

        if (!__all(tmax - m <= 11.5f)) {         // rescale only when max grows
            const float nm = fmaxf(m, tmax);
            const float esc = exp2f(m - nm);     // scale for query fr
            float es4[4];
#pragma unroll
            for (int r = 0; r < 4; ++r) es4[r] = __shfl(esc, 4 * g + r);
#pragma unroll
            for (int et = 0; et < 4; ++et)
#pragma unroll
                for (int r = 0; r < 4; ++r) o[et][r] *= es4[r];
            l *= esc;
            m = nm;
        }

#pragma unroll
        for (int s = 0; s < 4; ++s)
#pragma unroll
            for (int r = 0; r < 4; ++r) sc[s][r] = exp2f(sc[s][r] - m);
        float tsum = ((sc[0][0] + sc[0][1]) + (sc[0][2] + sc[0][3]))
                   + ((sc[1][0] + sc[1][1]) + (sc[1][2] + sc[1][3]))
                   + ((sc[2][0] + sc[2][1]) + (sc[2][2] + sc[2][3]))
                   + ((sc[3][0] + sc[3][1]) + (sc[3][2] + sc[3][3]));
        tsum += __shfl_xor(tsum, 16);
        tsum += __shfl_xor(tsum, 32);
        l += tsum;

#pragma unroll
        for (int s = 0; s < 4; ++s) {
            pk[s][0] = (unsigned)f2bf(sc[s][0]) | ((unsigned)f2bf(sc[s][1]) << 16);
            pk[s][1] = (unsigned)f2bf(sc[s][2]) | ((unsigned)f2bf(sc[s][3]) << 16);
        }

        // ---- PV on active 32-key chunks (2 per tile) ----
        short* pb = &Pc[w][0];
#pragma unroll
        for (int i = 0; i < 2; ++i) {
            const int slo = 4 * c + 2 * i, shi = slo + 1;   // global subtiles
            if (shi >= w && slo <= w + 16) {                // wave-uniform
                *(uint2v*)(pb + fr * PCST + 4 * g)      = (uint2v){pk[2 * i][0], pk[2 * i][1]};
                *(uint2v*)(pb + fr * PCST + 16 + 4 * g) = (uint2v){pk[2 * i + 1][0], pk[2 * i + 1][1]};
                const short8 pa = *(const short8*)(pb + fr * PCST + 8 * g);
                const int lc = 4 * i + g;                   // logical V 8-key chunk
                const short* vb8 = Vtile + fr * 64 + ((lc ^ (fr & 7)) * 8);
                __builtin_amdgcn_s_setprio(1);
#pragma unroll
                for (int et = 0; et < 4; ++et) {
                    const short8 vb = *(const short8*)(vb8 + et * 1024);
                    o[et] = MFMA_BF16(pa, vb, o[et], 0, 0, 0);
                }
                __builtin_amdgcn_s_setprio(0);
            }
        }

        // ---- stage tile c+2 into this slot (WAR-safe); gate tile c+1 ----
        if (c + 2 < 6) {
            __builtin_amdgcn_s_barrier();            // all waves done reading slot
            STAGESEG(slot, kb0 + c + 2);
            asm volatile("s_waitcnt vmcnt(2)" ::: "memory");   // tile c+1 landed
            __builtin_amdgcn_sched_barrier(0);
            __builtin_amdgcn_s_barrier();
        } else if (c == 4) {
            asm volatile("s_waitcnt vmcnt(0)" ::: "memory");   // tile 5 landed
            __builtin_amdgcn_sched_barrier(0);
            __builtin_amdgcn_s_barrier();
        }
    }
#undef STAGESEG

    const float inv = 1.0f / l;                    // valid for query = fr
    float inv4[4];
#pragma unroll
    for (int r = 0; r < 4; ++r) inv4[r] = __shfl(inv, 4 * g + r);

#pragma unroll
    for (int et = 0; et < 4; ++et)
#pragma unroll
        for (int r = 0; r < 4; ++r) {
            const int qi = q0 + w * 16 + 4 * g + r;
            const int dd = hh * HD + et * 16 + fr;
            out[((size_t)qi * NBATCH + bb) * DMODEL + dd] = o[et][r] * inv4[r];
        }
}

extern "C" void kernel_launch(void* const* d_in, const int* in_sizes, int n_in,
                              void* d_out, int out_size, void* d_ws, size_t ws_size,
                              hipStream_t stream) {
    (void)in_sizes; (void)n_in; (void)out_size; (void)ws_size;
    const float* val = (const float*)d_in[0];
    const float* Wq  = (const float*)d_in[1];
    const float* bq  = (const float*)d_in[2];
    const float* Wk  = (const float*)d_in[3];
    const float* bk  = (const float*)d_in[4];
    const float* Wv  = (const float*)d_in[5];
    const float* bv  = (const float*)d_in[6];
    float* out = (float*)d_out;

    char* ws = (char*)d_ws;
    const size_t SZ_X  = (size_t)MROWS * DMODEL * 2;
    const size_t SZ_W  = (size_t)DMODEL * DMODEL * 2;
    short* X  = (short*)(ws);
    short* WT = (short*)(ws + SZ_X);
    short* Qb = (short*)(ws + SZ_X + 3 * SZ_W);
    short* Kb = (short*)(ws + SZ_X + 3 * SZ_W + SZ_X);
    short* Vt = (short*)(ws + SZ_X + 3 * SZ_W + 2 * SZ_X);

    cvt_all_kernel<<<dim3(7008), dim3(256), 0, stream>>>(val, Wq, Wk, Wv, X, WT);
    gemm_qkv_kernel<<<dim3(768), dim3(256), 0, stream>>>(
        X, WT, bq, bk, bv, Qb, Kb, Vt);
    attn_kernel<<<dim3(768), dim3(512), 0, stream>>>(Qb, Kb, Vt, out);
}